// Round 15
// baseline (409.061 us; speedup 1.0000x reference)
//
#include <hip/hip_runtime.h>
#include <cstdint>
#include <cstddef>

#define BSZ    32
#define SEQL   2048
#define ENCD   512
#define DE     1024   // DEC + ENC
#define NHEADS 8
#define IHD    1024   // INTERM * HEADS

typedef unsigned short u16;
typedef __bf16 bf16x8 __attribute__((ext_vector_type(8)));
typedef float floatx4 __attribute__((ext_vector_type(4)));
typedef unsigned short u16x8 __attribute__((ext_vector_type(8)));

__device__ __forceinline__ u16 f2bf(float f) {
    unsigned int u = __float_as_uint(f);
    u = (u + 0x7FFFu + ((u >> 16) & 1u)) >> 16;   // RNE
    return (u16)u;
}
__device__ __forceinline__ float bf2f(u16 v) {
    return __uint_as_float(((unsigned int)v) << 16);
}
__device__ __forceinline__ float softplus_f(float x) {
    return fmaxf(x, 0.0f) + log1pf(__expf(-fabsf(x)));
}
__device__ __forceinline__ float tanh_fast(float x) {
    const float e = __expf(2.0f * x);
    return 1.0f - 2.0f / (e + 1.0f);
}
__device__ __forceinline__ void async_cp16(u16* lds, const u16* g) {
    __builtin_amdgcn_global_load_lds(
        (const __attribute__((address_space(1))) unsigned int*)g,
        (__attribute__((address_space(3))) unsigned int*)lds, 16, 0, 0);
}

// ---------------------------------------------------------------------------
// Producer kernel (289 blocks):
//   bid <  128 : WvT[n][k] = bf16(Wv[k][n]) via 64x64 LDS tile transpose
//   bid == 128 : Wf -> bf16 packed in MFMA B-fragment order
//   129..256   : query PARTIALS, (ct,kg) = (col-tile of 32, k-chunk of 256):
//                each block stages dec[32b][256k] in LDS and computes
//                qpart[kg][b][col] for ALL batches -> Wq read ONCE (4 MB,
//                was 134 MB with per-batch blocks).
//   257..288   : beta/kappa per-batch blocks (unchanged)
// ---------------------------------------------------------------------------
__global__ __launch_bounds__(256) void pre_kernel(
    const float* __restrict__ Wv, const float* __restrict__ Wf,
    u16* __restrict__ WvT, u16* __restrict__ wfb,
    const float* __restrict__ dec, const float* __restrict__ kappa_in,
    const float* __restrict__ Wq,
    const float* __restrict__ Wb, const float* __restrict__ bb,
    const float* __restrict__ Wk, const float* __restrict__ bk,
    float* __restrict__ qpart, float* __restrict__ beta_ws,
    float* __restrict__ kappa_out)
{
    __shared__ float sh[8192];      // 32 KB: dec stage / transpose / reduce
    const int bid = blockIdx.x, tid = threadIdx.x;

    if (bid < 128) {                // ---- Wv transpose tile
        const int nt = bid & 15, kt = bid >> 4;
        for (int i = tid; i < 4096; i += 256) {
            const int kk = i >> 6, nn = i & 63;
            sh[kk * 65 + nn] = Wv[(size_t)(kt * 64 + kk) * IHD + nt * 64 + nn];
        }
        __syncthreads();
        for (int i = tid; i < 4096; i += 256) {
            const int nn = i >> 6, kk = i & 63;
            WvT[(size_t)(nt * 64 + nn) * 512 + kt * 64 + kk] = f2bf(sh[kk * 65 + nn]);
        }
        return;
    }
    if (bid == 128) {               // ---- Wf pack
        for (int i = tid; i < 8192; i += 256) {
            const int j   = i & 7;
            const int fr8 = (i >> 3) & 7;
            const int qd  = (i >> 6) & 3;
            const int ks  = (i >> 8) & 3;
            const int nn  = i >> 10;
            const int row = nn * 128 + ks * 32 + qd * 8 + j;
            wfb[i] = f2bf(Wf[row * NHEADS + fr8]);
        }
        return;
    }
    const int p = bid - 129;
    if (p < 128) {                  // ---- query partials (ct, kg)
        const int ct = p & 31, kg = p >> 5;
        // stage dec[32][256] (coalesced: 256 consecutive floats per batch row)
        for (int i = tid; i < 8192; i += 256) {
            const int bb2 = i >> 8, kk = i & 255;
            sh[i] = dec[(size_t)bb2 * DE + kg * 256 + kk];
        }
        __syncthreads();
        const int cl = tid & 31, bg = tid >> 5;    // 8 batch-groups of 4
        const int col = ct * 32 + cl;
        float a0 = 0.f, a1 = 0.f, a2 = 0.f, a3 = 0.f;
        const float* wq = Wq + (size_t)kg * 256 * IHD + col;
        #pragma unroll 8
        for (int k = 0; k < 256; ++k) {
            const float wv = wq[(size_t)k * IHD];  // broadcast across bg groups
            a0 = fmaf(sh[(bg * 4 + 0) * 256 + k], wv, a0);
            a1 = fmaf(sh[(bg * 4 + 1) * 256 + k], wv, a1);
            a2 = fmaf(sh[(bg * 4 + 2) * 256 + k], wv, a2);
            a3 = fmaf(sh[(bg * 4 + 3) * 256 + k], wv, a3);
        }
        float* outp = qpart + (size_t)kg * (BSZ * IHD) + col;
        outp[(size_t)(bg * 4 + 0) * IHD] = a0;
        outp[(size_t)(bg * 4 + 1) * IHD] = a1;
        outp[(size_t)(bg * 4 + 2) * IHD] = a2;
        outp[(size_t)(bg * 4 + 3) * IHD] = a3;
        return;
    }
    // ---- beta/kappa (one block per batch)
    const int b = p - 128;
    float* s_dec = sh;
    float* s_red = sh + DE;
    for (int i = tid; i < DE; i += 256) s_dec[i] = dec[b * DE + i];
    __syncthreads();
    const int h = tid & 7, kg = tid >> 3;
    float ab = 0.f, ak = 0.f;
    for (int k = kg * 32; k < kg * 32 + 32; ++k) {
        const float d = s_dec[k];
        ab = fmaf(d, Wb[k * NHEADS + h], ab);
        ak = fmaf(d, Wk[k * NHEADS + h], ak);
    }
    s_red[tid] = ab;
    __syncthreads();
    for (int off = 128; off >= 8; off >>= 1) {
        if (tid < off) s_red[tid] += s_red[tid + off];
        __syncthreads();
    }
    const float abT = (tid < 8) ? s_red[tid] : 0.f;
    __syncthreads();
    s_red[tid] = ak;
    __syncthreads();
    for (int off = 128; off >= 8; off >>= 1) {
        if (tid < off) s_red[tid] += s_red[tid + off];
        __syncthreads();
    }
    if (tid < 8) {
        beta_ws[b * NHEADS + tid]   = softplus_f(bb[tid] + abT);
        kappa_out[b * NHEADS + tid] = kappa_in[b * NHEADS + tid]
                                    + softplus_f(bk[tid] + s_red[tid]);
    }
}

// ---------------------------------------------------------------------------
// Main fused kernel (round-12/14 structure):
//  - prologue converts own 128 enc rows fp32->bf16 (16-deep batches), drain.
//  - main loop: A+B via global_load_lds double-buffer, BK=64 (128B rows,
//    conflict-free XOR swizzle), counted vmcnt UNIFORM vmcnt(8) (epilogue
//    operand loads moved OUT of the counted region -> simpler & proven in
//    rounds 4/5), vmcnt(0) only at the very last tile; setprio on MFMA.
//  - epilogue: qv = (((qpart0+qpart1)+qpart2)+qpart3 + bq) + bv per column
//    (fixed fold order; L1/L2-warm loads overlapped with the barrier).
//  - tail: score -> s_score -> coalesced 4KB store; ctx partial 16-deep.
// LDS: buf0 32K | buf1 32K | tT 32K aliases buf1 | s_score 4K = 68K.
// ---------------------------------------------------------------------------
#define BM 128

__global__ __launch_bounds__(256, 2) void gemm_score_ctx_kernel(
    const float* __restrict__ enc, u16* __restrict__ encb,
    const u16* __restrict__ wvT,
    const u16* __restrict__ wfb2, const float* __restrict__ bf_g,
    const float* __restrict__ mask, const float* __restrict__ qpart,
    const float* __restrict__ bq_g, const float* __restrict__ bv_g,
    const float* __restrict__ beta_ws, const float* __restrict__ kappa_out,
    float* __restrict__ score_out, float* __restrict__ ctx_part)
{
    __shared__ __align__(16) unsigned char smem[69632];
    u16*   tT      = (u16*)(smem + 32768);     // aliases buf1
    float* s_score = (float*)(smem + 65536);

    const int tid  = threadIdx.x;
    const int m0   = blockIdx.x * BM;
    const int b    = blockIdx.x >> 4;           // 16 m-tiles per batch
    const int sc   = blockIdx.x & 15;           // seq chunk for ctx_part
    const int lane = tid & 63;
    const int w    = tid >> 6;
    const int wr   = w >> 1, wc = w & 1;
    const int fr   = lane & 15, quad = lane >> 4;

    // ---- prologue: convert own 128x512 enc rows fp32 -> bf16 (global)
    {
        const float4* src = (const float4*)enc + (size_t)m0 * 128;
        u16x8* dst = (u16x8*)(encb + (size_t)m0 * 512);
        for (int base = 0; base < 32; base += 8) {
            float4 av[8], bw[8];
            #pragma unroll
            for (int u = 0; u < 8; ++u) {
                const int i = (base + u) * 256 + tid;
                av[u] = src[i * 2];
                bw[u] = src[i * 2 + 1];
            }
            #pragma unroll
            for (int u = 0; u < 8; ++u) {
                const int i = (base + u) * 256 + tid;
                u16x8 o;
                o[0] = f2bf(av[u].x); o[1] = f2bf(av[u].y);
                o[2] = f2bf(av[u].z); o[3] = f2bf(av[u].w);
                o[4] = f2bf(bw[u].x); o[5] = f2bf(bw[u].y);
                o[6] = f2bf(bw[u].z); o[7] = f2bf(bw[u].w);
                dst[i] = o;
            }
        }
        asm volatile("s_waitcnt vmcnt(0)" ::: "memory");
        __builtin_amdgcn_sched_barrier(0);
        __builtin_amdgcn_s_barrier();   // all waves' stores in L2 before staging
    }

    // staging constants (8 chunks of 16B per 128x64 tile row-space)
    int mA[4], csA[4];
    #pragma unroll
    for (int r = 0; r < 4; ++r) {
        const int c = r * 256 + tid;
        mA[r]  = c >> 3;
        csA[r] = (c & 7) ^ (mA[r] & 7);
    }

    // stage A(128x64)+B(128x64) bf16 tile pair for flat iter it=(nn,kt):
    // 8 global_load_lds per thread
    auto stage = [&](int bufsel, int it) {
        u16* Ab = (u16*)(smem + bufsel * 32768);
        u16* Bb = Ab + 8192;
        const int nn2 = it >> 3, kt2 = it & 7;
        const size_t aoff = (size_t)kt2 * 64;
        const size_t boff = (size_t)nn2 * (128 * 512) + (size_t)kt2 * 64;
        #pragma unroll
        for (int r = 0; r < 4; ++r) {
            async_cp16(Ab + (r * 256 + (tid & 192)) * 8,
                       encb + (size_t)(m0 + mA[r]) * 512 + aoff + csA[r] * 8);
            async_cp16(Bb + (size_t)(r * 256 + (tid & 192)) * 8,
                       wvT + (size_t)mA[r] * 512 + boff + csA[r] * 8);
        }
    };

    floatx4 acc2[2] = {};

    stage(0, 0);

    for (int nn = 0; nn < 8; ++nn) {
        const int n0 = nn * 128;
        floatx4 acc[4][4] = {};

        #pragma unroll
        for (int kt = 0; kt < 8; ++kt) {
            const int it = nn * 8 + kt;
            if (kt < 7 || nn < 7)
                stage((it + 1) & 1, it + 1);
            // counted wait: tile it's 8 ops are the oldest; leave the newest
            // 8 (tile it+1) in flight. Only the very last tile drains fully.
            if (kt == 7 && nn == 7) {
                asm volatile("s_waitcnt vmcnt(0)" ::: "memory");
            } else {
                asm volatile("s_waitcnt vmcnt(8)" ::: "memory");
            }
            __builtin_amdgcn_sched_barrier(0);
            __builtin_amdgcn_s_barrier();          // A: tile it landed

            u16* Ab = (u16*)(smem + (it & 1) * 32768);
            u16* Bb = Ab + 8192;
            __builtin_amdgcn_s_setprio(1);
            #pragma unroll
            for (int s2 = 0; s2 < 2; ++s2) {
                bf16x8 af[4], bfr[4];
                #pragma unroll
                for (int mt = 0; mt < 4; ++mt) {
                    const int ma = wr * 64 + mt * 16 + fr;
                    const int ca = (s2 * 4 + quad) ^ (ma & 7);
                    af[mt] = *(const bf16x8*)&Ab[ma * 64 + ca * 8];
                }
                #pragma unroll
                for (int nt = 0; nt < 4; ++nt) {
                    const int nb = wc * 64 + nt * 16 + fr;
                    const int cb = (s2 * 4 + quad) ^ (nb & 7);
                    bfr[nt] = *(const bf16x8*)&Bb[nb * 64 + cb * 8];
                }
                #pragma unroll
                for (int mt = 0; mt < 4; ++mt)
                    #pragma unroll
                    for (int nt = 0; nt < 4; ++nt)
                        acc[mt][nt] = __builtin_amdgcn_mfma_f32_16x16x32_bf16(
                            af[mt], bfr[nt], acc[mt][nt], 0, 0, 0);
            }
            __builtin_amdgcn_s_setprio(0);
            __builtin_amdgcn_sched_barrier(0);
            __builtin_amdgcn_s_barrier();          // B: buf (it&1) free
        }

        // ---- epilogue operands (compiler-managed; outside counted region)
        float qv[4];
        bf16x8 wfr[4];
        #pragma unroll
        for (int nt = 0; nt < 4; ++nt) {
            const int col = n0 + wc * 64 + nt * 16 + fr;
            float t = qpart[(size_t)b * IHD + col];                 // kg=0
            t += qpart[(size_t)(BSZ * IHD) * 1 + (size_t)b * IHD + col];
            t += qpart[(size_t)(BSZ * IHD) * 2 + (size_t)b * IHD + col];
            t += qpart[(size_t)(BSZ * IHD) * 3 + (size_t)b * IHD + col];
            qv[nt] = (t + bq_g[col]) + bv_g[col];
        }
        #pragma unroll
        for (int ks = 0; ks < 4; ++ks)
            wfr[ks] = *(const bf16x8*)&wfb2[((nn * 4 + ks) * 4 + quad) * 64
                                            + (fr & 7) * 8];

        // ---- epilogue A: t = tanh(value + query) -> tT (bf16, XOR-swizzled)
        // tT aliases buf1 (just consumed at kt=7; next-nn prefetch is in buf0)
        #pragma unroll
        for (int mt = 0; mt < 4; ++mt) {
            #pragma unroll
            for (int nt = 0; nt < 4; ++nt) {
                const int col = wc * 64 + nt * 16 + fr;
                #pragma unroll
                for (int reg = 0; reg < 4; ++reg) {
                    const int row = wr * 64 + mt * 16 + quad * 4 + reg;
                    ((__bf16*)tT)[row * 128 + (col ^ ((row & 7) << 3))] =
                        (__bf16)tanh_fast(acc[mt][nt][reg] + qv[nt]);
                }
            }
        }
        asm volatile("s_waitcnt lgkmcnt(0)" ::: "memory");
        __builtin_amdgcn_sched_barrier(0);
        __builtin_amdgcn_s_barrier();              // C: tT visible

        // ---- epilogue B: stage-2 MFMA  P += t(128x128) @ Wf_slice(128x8)
        #pragma unroll
        for (int t = 0; t < 2; ++t) {
            const int row = w * 32 + t * 16 + fr;
            #pragma unroll
            for (int ks = 0; ks < 4; ++ks) {
                const bf16x8 ta = *(const bf16x8*)
                    &tT[row * 128 + ((ks * 32 + quad * 8) ^ ((row & 7) << 3))];
                acc2[t] = __builtin_amdgcn_mfma_f32_16x16x32_bf16(ta, wfr[ks], acc2[t], 0, 0, 0);
            }
        }
        __builtin_amdgcn_sched_barrier(0);
        __builtin_amdgcn_s_barrier();              // D: tT reads done before
                                                   //    next nn stages buf1
    }

    // ---- score: softplus(P + bf) * mask * exp(-beta*(kappa-u)^2) -> s_score
    if (fr < NHEADS) {
        const float bfh = bf_g[fr];
        const float bet = beta_ws[b * NHEADS + fr];
        const float kap = kappa_out[b * NHEADS + fr];
        #pragma unroll
        for (int t = 0; t < 2; ++t) {
            #pragma unroll
            for (int reg = 0; reg < 4; ++reg) {
                const int row  = w * 32 + t * 16 + quad * 4 + reg;  // 0..127
                const int grow = m0 + row;
                const int s = grow & 2047;
                const float alpha = softplus_f(acc2[t][reg] + bfh) * mask[grow];
                const float du = kap - (float)s;
                s_score[row * NHEADS + fr] = alpha * __expf(-bet * du * du);
            }
        }
    }
    asm volatile("s_waitcnt lgkmcnt(0)" ::: "memory");
    __builtin_amdgcn_s_barrier();

    // ---- coalesced score store: one contiguous 4KB block
    {
        const float4* src4 = (const float4*)s_score;
        float4* dst4 = (float4*)(score_out + (size_t)m0 * NHEADS);
        dst4[tid] = src4[tid];     // 256 threads x 16B = 4KB = 128x8 floats
    }

    // ---- fused context partial over this block's 128 rows:
    //      part[sc][b][h][e] = sum_s score[s,h] * enc[s,e]
    //      16-deep load batching (enc_bf re-read misses L2: 8MB/XCD > 4MB).
    {
        float acc0[8] = {}, acc1[8] = {};
        const u16* ep = encb + (size_t)m0 * 512 + lane * 8;
        for (int s0 = 0; s0 < 128; s0 += 16) {
            u16x8 ev[16];
            #pragma unroll
            for (int u = 0; u < 16; ++u)
                ev[u] = *(const u16x8*)(ep + (size_t)(s0 + u) * 512);
            #pragma unroll
            for (int u = 0; u < 16; ++u) {
                const float2 sc2 = *(const float2*)&s_score[(s0 + u) * NHEADS + 2 * w];
                #pragma unroll
                for (int j = 0; j < 8; ++j) {
                    const float e = bf2f(ev[u][j]);
                    acc0[j] = fmaf(sc2.x, e, acc0[j]);
                    acc1[j] = fmaf(sc2.y, e, acc1[j]);
                }
            }
        }
        const int e8 = lane * 8;
        float* outp = ctx_part + ((size_t)sc * BSZ + b) * (NHEADS * ENCD);
        *(float4*)&outp[(2 * w + 0) * ENCD + e8]     = make_float4(acc0[0], acc0[1], acc0[2], acc0[3]);
        *(float4*)&outp[(2 * w + 0) * ENCD + e8 + 4] = make_float4(acc0[4], acc0[5], acc0[6], acc0[7]);
        *(float4*)&outp[(2 * w + 1) * ENCD + e8]     = make_float4(acc1[0], acc1[1], acc1[2], acc1[3]);
        *(float4*)&outp[(2 * w + 1) * ENCD + e8 + 4] = make_float4(acc1[4], acc1[5], acc1[6], acc1[7]);
    }
}

// ---------------------------------------------------------------------------
// ctx_ws[i] = sum_sc part[sc][i]   (i < 131072)
// NOTE: ctx_ws aliases qpart (same 512KB slot) -- lifetimes disjoint:
// qpart is dead once gemm finishes; reduce runs strictly after gemm.
// ---------------------------------------------------------------------------
__global__ __launch_bounds__(256) void ctx_reduce_kernel(
    const float* __restrict__ part, float* __restrict__ ctx_ws)
{
    const int i = blockIdx.x * 256 + threadIdx.x;
    float a = 0.f;
    #pragma unroll
    for (int sc = 0; sc < 16; ++sc)
        a += part[(size_t)sc * 131072 + i];
    ctx_ws[i] = a;
}

// ---------------------------------------------------------------------------
// out_ctx[b,j] += ctx[b, k0..k0+128] @ Wfc[k0..k0+128, j]  (+bfc at ks==0)
// grid (16, 32): 512 blocks = 2/CU.
// ---------------------------------------------------------------------------
__global__ __launch_bounds__(256) void final_kernel(
    const float* __restrict__ ctx_ws, const float* __restrict__ Wfc,
    const float* __restrict__ bfc, float* __restrict__ out_ctx)
{
    __shared__ float s_ctx[32][128];
    const int jc = blockIdx.x, ks = blockIdx.y, tid = threadIdx.x;
    const int jl = tid & 31, bg = tid >> 5;
    const int j = jc * 32 + jl;
    const int k0 = ks * 128;

    for (int i = tid; i < 32 * 128; i += 256) {
        const int bb2 = i >> 7, kk = i & 127;
        s_ctx[bb2][kk] = ctx_ws[(size_t)bb2 * (NHEADS * ENCD) + k0 + kk];
    }
    __syncthreads();

    float a0 = 0.f, a1 = 0.f, a2 = 0.f, a3 = 0.f;
    for (int kk = 0; kk < 128; ++kk) {
        const float wv = Wfc[(size_t)(k0 + kk) * ENCD + j];
        a0 = fmaf(s_ctx[bg * 4 + 0][kk], wv, a0);
        a1 = fmaf(s_ctx[bg * 4 + 1][kk], wv, a1);
        a2 = fmaf(s_ctx[bg * 4 + 2][kk], wv, a2);
        a3 = fmaf(s_ctx[bg * 4 + 3][kk], wv, a3);
    }
    const float bias = (ks == 0) ? bfc[j] : 0.0f;
    atomicAdd(&out_ctx[(bg * 4 + 0) * ENCD + j], a0 + bias);
    atomicAdd(&out_ctx[(bg * 4 + 1) * ENCD + j], a1 + bias);
    atomicAdd(&out_ctx[(bg * 4 + 2) * ENCD + j], a2 + bias);
    atomicAdd(&out_ctx[(bg * 4 + 3) * ENCD + j], a3 + bias);
}

// ---------------------------------------------------------------------------
extern "C" void kernel_launch(void* const* d_in, const int* in_sizes, int n_in,
                              void* d_out, int out_size, void* d_ws, size_t ws_size,
                              hipStream_t stream)
{
    const float* enc   = (const float*)d_in[0];
    const float* dec   = (const float*)d_in[1];
    const float* kapin = (const float*)d_in[2];
    const float* mask  = (const float*)d_in[3];
    const float* Wv    = (const float*)d_in[4];
    const float* bv    = (const float*)d_in[5];
    const float* Wq    = (const float*)d_in[6];
    const float* bq    = (const float*)d_in[7];
    const float* Wf    = (const float*)d_in[8];
    const float* bf    = (const float*)d_in[9];
    const float* Wb    = (const float*)d_in[10];
    const float* bb    = (const float*)d_in[11];
    const float* Wk    = (const float*)d_in[12];
    const float* bk    = (const float*)d_in[13];
    const float* Wfc   = (const float*)d_in[14];
    const float* bfc   = (const float*)d_in[15];

    // outputs: context(32*512) | kappa(32*8) | score(32*2048*8)
    float* out       = (float*)d_out;
    float* out_ctx   = out;
    float* out_kappa = out + 16384;
    float* out_score = out + 16640;

    // workspace layout (bytes) -- total unchanged at 77218832
    char* w = (char*)d_ws;
    u16*   enc_bf   = (u16*)w;                     // 67108864 B
    float* ctx_part = (float*)(w + 67108864);      //  8388608 B
    u16*   wvT      = (u16*)(w + 75497472);        //  1048576 B
    // (w + 76546048): 131072 B free (old q_ws slot)
    float* beta_ws  = (float*)(w + 76677120);      //     1024 B
    float* qpart    = (float*)(w + 76678144);      //   524288 B (pre->gemm)
    float* ctx_ws   = (float*)(w + 76678144);      //   524288 B (reduce->final;
                                                   //   aliases qpart, disjoint)
    u16*   wfb      = (u16*)(w + 77202432);        //    16400 B (16384 used)

    hipMemsetAsync(out_ctx, 0, 16384 * sizeof(float), stream);

    pre_kernel<<<dim3(289), dim3(256), 0, stream>>>(
        Wv, Wf, wvT, wfb,
        dec, kapin, Wq, Wb, bb, Wk, bk, qpart, beta_ws, out_kappa);

    gemm_score_ctx_kernel<<<dim3((BSZ * SEQL) / BM), dim3(256), 0, stream>>>(
        enc, enc_bf, wvT, wfb, bf, mask, qpart, bq, bv, beta_ws, out_kappa,
        out_score, ctx_part);

    ctx_reduce_kernel<<<dim3(512), dim3(256), 0, stream>>>(ctx_part, ctx_ws);

    final_kernel<<<dim3(16, 32), dim3(256), 0, stream>>>(
        ctx_ws, Wfc, bfc, out_ctx);
}

// Round 16
// 384.084 us; speedup vs baseline: 1.0650x; 1.0650x over previous
//
#include <hip/hip_runtime.h>
#include <cstdint>
#include <cstddef>

#define BSZ    32
#define SEQL   2048
#define ENCD   512
#define DE     1024   // DEC + ENC
#define NHEADS 8
#define IHD    1024   // INTERM * HEADS

typedef unsigned short u16;
typedef __bf16 bf16x8 __attribute__((ext_vector_type(8)));
typedef float floatx4 __attribute__((ext_vector_type(4)));
typedef unsigned short u16x8 __attribute__((ext_vector_type(8)));

__device__ __forceinline__ u16 f2bf(float f) {
    unsigned int u = __float_as_uint(f);
    u = (u + 0x7FFFu + ((u >> 16) & 1u)) >> 16;   // RNE
    return (u16)u;
}
__device__ __forceinline__ float bf2f(u16 v) {
    return __uint_as_float(((unsigned int)v) << 16);
}
__device__ __forceinline__ float softplus_f(float x) {
    return fmaxf(x, 0.0f) + log1pf(__expf(-fabsf(x)));
}
__device__ __forceinline__ float tanh_fast(float x) {
    const float e = __expf(2.0f * x);
    return 1.0f - 2.0f / (e + 1.0f);
}
__device__ __forceinline__ void async_cp16(u16* lds, const u16* g) {
    __builtin_amdgcn_global_load_lds(
        (const __attribute__((address_space(1))) unsigned int*)g,
        (__attribute__((address_space(3))) unsigned int*)lds, 16, 0, 0);
}

// ---------------------------------------------------------------------------
// Producer kernel (289 blocks) -- round-15 version (Wq read once, measured):
//   bid <  128 : WvT[n][k] = bf16(Wv[k][n]) via 64x64 LDS tile transpose
//   bid == 128 : Wf -> bf16 packed in MFMA B-fragment order
//   129..256   : query PARTIALS (ct,kg): qpart[kg][b][col], Wq read once
//   257..288   : beta/kappa per-batch blocks
// ---------------------------------------------------------------------------
__global__ __launch_bounds__(256) void pre_kernel(
    const float* __restrict__ Wv, const float* __restrict__ Wf,
    u16* __restrict__ WvT, u16* __restrict__ wfb,
    const float* __restrict__ dec, const float* __restrict__ kappa_in,
    const float* __restrict__ Wq,
    const float* __restrict__ Wb, const float* __restrict__ bb,
    const float* __restrict__ Wk, const float* __restrict__ bk,
    float* __restrict__ qpart, float* __restrict__ beta_ws,
    float* __restrict__ kappa_out)
{
    __shared__ float sh[8192];      // 32 KB: dec stage / transpose / reduce
    const int bid = blockIdx.x, tid = threadIdx.x;

    if (bid < 128) {                // ---- Wv transpose tile
        const int nt = bid & 15, kt = bid >> 4;
        for (int i = tid; i < 4096; i += 256) {
            const int kk = i >> 6, nn = i & 63;
            sh[kk * 65 + nn] = Wv[(size_t)(kt * 64 + kk) * IHD + nt * 64 + nn];
        }
        __syncthreads();
        for (int i = tid; i < 4096; i += 256) {
            const int nn = i >> 6, kk = i & 63;
            WvT[(size_t)(nt * 64 + nn) * 512 + kt * 64 + kk] = f2bf(sh[kk * 65 + nn]);
        }
        return;
    }
    if (bid == 128) {               // ---- Wf pack
        for (int i = tid; i < 8192; i += 256) {
            const int j   = i & 7;
            const int fr8 = (i >> 3) & 7;
            const int qd  = (i >> 6) & 3;
            const int ks  = (i >> 8) & 3;
            const int nn  = i >> 10;
            const int row = nn * 128 + ks * 32 + qd * 8 + j;
            wfb[i] = f2bf(Wf[row * NHEADS + fr8]);
        }
        return;
    }
    const int p = bid - 129;
    if (p < 128) {                  // ---- query partials (ct, kg)
        const int ct = p & 31, kg = p >> 5;
        for (int i = tid; i < 8192; i += 256) {
            const int bb2 = i >> 8, kk = i & 255;
            sh[i] = dec[(size_t)bb2 * DE + kg * 256 + kk];
        }
        __syncthreads();
        const int cl = tid & 31, bg = tid >> 5;    // 8 batch-groups of 4
        const int col = ct * 32 + cl;
        float a0 = 0.f, a1 = 0.f, a2 = 0.f, a3 = 0.f;
        const float* wq = Wq + (size_t)kg * 256 * IHD + col;
        #pragma unroll 8
        for (int k = 0; k < 256; ++k) {
            const float wv = wq[(size_t)k * IHD];
            a0 = fmaf(sh[(bg * 4 + 0) * 256 + k], wv, a0);
            a1 = fmaf(sh[(bg * 4 + 1) * 256 + k], wv, a1);
            a2 = fmaf(sh[(bg * 4 + 2) * 256 + k], wv, a2);
            a3 = fmaf(sh[(bg * 4 + 3) * 256 + k], wv, a3);
        }
        float* outp = qpart + (size_t)kg * (BSZ * IHD) + col;
        outp[(size_t)(bg * 4 + 0) * IHD] = a0;
        outp[(size_t)(bg * 4 + 1) * IHD] = a1;
        outp[(size_t)(bg * 4 + 2) * IHD] = a2;
        outp[(size_t)(bg * 4 + 3) * IHD] = a3;
        return;
    }
    // ---- beta/kappa (one block per batch)
    const int b = p - 128;
    float* s_dec = sh;
    float* s_red = sh + DE;
    for (int i = tid; i < DE; i += 256) s_dec[i] = dec[b * DE + i];
    __syncthreads();
    const int h = tid & 7, kg = tid >> 3;
    float ab = 0.f, ak = 0.f;
    for (int k = kg * 32; k < kg * 32 + 32; ++k) {
        const float d = s_dec[k];
        ab = fmaf(d, Wb[k * NHEADS + h], ab);
        ak = fmaf(d, Wk[k * NHEADS + h], ak);
    }
    s_red[tid] = ab;
    __syncthreads();
    for (int off = 128; off >= 8; off >>= 1) {
        if (tid < off) s_red[tid] += s_red[tid + off];
        __syncthreads();
    }
    const float abT = (tid < 8) ? s_red[tid] : 0.f;
    __syncthreads();
    s_red[tid] = ak;
    __syncthreads();
    for (int off = 128; off >= 8; off >>= 1) {
        if (tid < off) s_red[tid] += s_red[tid + off];
        __syncthreads();
    }
    if (tid < 8) {
        beta_ws[b * NHEADS + tid]   = softplus_f(bb[tid] + abT);
        kappa_out[b * NHEADS + tid] = kappa_in[b * NHEADS + tid]
                                    + softplus_f(bk[tid] + s_red[tid]);
    }
}

// ---------------------------------------------------------------------------
// Main fused kernel:
//  - prologue: (a) enc fp32->bf16 conversion (16-deep batches, BW-bound) AND
//    (b) s_qv[col] = sum(qpart kg=0..3) + bq + bv for this batch's 1024 cols
//    -- qpart reduce rides the prologue's BW slack; epilogue reads qv from
//    LDS (fixes round-15's serial epilogue load stall while keeping the
//    Wq-once pre_kernel win). Covered by the existing vmcnt(0)+barrier.
//  - main loop: round-12 proven schedule; uniform counted vmcnt(8),
//    vmcnt(0) only at last tile; setprio on MFMA cluster.
//  - tail: score -> s_score -> coalesced 4KB store; ctx partial 16-deep.
// LDS: buf0 32K | buf1 32K | tT 32K aliases buf1 | s_score 4K | s_qv 4K = 72K.
// ---------------------------------------------------------------------------
#define BM 128

__global__ __launch_bounds__(256, 2) void gemm_score_ctx_kernel(
    const float* __restrict__ enc, u16* __restrict__ encb,
    const u16* __restrict__ wvT,
    const u16* __restrict__ wfb2, const float* __restrict__ bf_g,
    const float* __restrict__ mask, const float* __restrict__ qpart,
    const float* __restrict__ bq_g, const float* __restrict__ bv_g,
    const float* __restrict__ beta_ws, const float* __restrict__ kappa_out,
    float* __restrict__ score_out, float* __restrict__ ctx_part)
{
    __shared__ __align__(16) unsigned char smem[73728];
    u16*   tT      = (u16*)(smem + 32768);     // aliases buf1
    float* s_score = (float*)(smem + 65536);
    float* s_qv    = (float*)(smem + 69632);   // [1024] query+bq+bv for batch b

    const int tid  = threadIdx.x;
    const int m0   = blockIdx.x * BM;
    const int b    = blockIdx.x >> 4;           // 16 m-tiles per batch
    const int sc   = blockIdx.x & 15;           // seq chunk for ctx_part
    const int lane = tid & 63;
    const int w    = tid >> 6;
    const int wr   = w >> 1, wc = w & 1;
    const int fr   = lane & 15, quad = lane >> 4;

    // ---- prologue: enc conversion + qv reduce into LDS
    {
        // (b) qv reduce: 4 cols per thread, fold order = round-15 (verified)
        #pragma unroll
        for (int r = 0; r < 4; ++r) {
            const int col = r * 256 + tid;
            float t = qpart[(size_t)b * IHD + col];
            t += qpart[(size_t)(BSZ * IHD) * 1 + (size_t)b * IHD + col];
            t += qpart[(size_t)(BSZ * IHD) * 2 + (size_t)b * IHD + col];
            t += qpart[(size_t)(BSZ * IHD) * 3 + (size_t)b * IHD + col];
            s_qv[col] = (t + bq_g[col]) + bv_g[col];
        }
        // (a) enc conversion, 16-deep load batches
        const float4* src = (const float4*)enc + (size_t)m0 * 128;
        u16x8* dst = (u16x8*)(encb + (size_t)m0 * 512);
        for (int base = 0; base < 32; base += 8) {
            float4 av[8], bw[8];
            #pragma unroll
            for (int u = 0; u < 8; ++u) {
                const int i = (base + u) * 256 + tid;
                av[u] = src[i * 2];
                bw[u] = src[i * 2 + 1];
            }
            #pragma unroll
            for (int u = 0; u < 8; ++u) {
                const int i = (base + u) * 256 + tid;
                u16x8 o;
                o[0] = f2bf(av[u].x); o[1] = f2bf(av[u].y);
                o[2] = f2bf(av[u].z); o[3] = f2bf(av[u].w);
                o[4] = f2bf(bw[u].x); o[5] = f2bf(bw[u].y);
                o[6] = f2bf(bw[u].z); o[7] = f2bf(bw[u].w);
                dst[i] = o;
            }
        }
        asm volatile("s_waitcnt vmcnt(0) lgkmcnt(0)" ::: "memory");
        __builtin_amdgcn_sched_barrier(0);
        __builtin_amdgcn_s_barrier();   // stores in L2 + s_qv visible
    }

    // staging constants (8 chunks of 16B per 128x64 tile row-space)
    int mA[4], csA[4];
    #pragma unroll
    for (int r = 0; r < 4; ++r) {
        const int c = r * 256 + tid;
        mA[r]  = c >> 3;
        csA[r] = (c & 7) ^ (mA[r] & 7);
    }

    // stage A(128x64)+B(128x64) bf16 tile pair for flat iter it=(nn,kt):
    // 8 global_load_lds per thread
    auto stage = [&](int bufsel, int it) {
        u16* Ab = (u16*)(smem + bufsel * 32768);
        u16* Bb = Ab + 8192;
        const int nn2 = it >> 3, kt2 = it & 7;
        const size_t aoff = (size_t)kt2 * 64;
        const size_t boff = (size_t)nn2 * (128 * 512) + (size_t)kt2 * 64;
        #pragma unroll
        for (int r = 0; r < 4; ++r) {
            async_cp16(Ab + (r * 256 + (tid & 192)) * 8,
                       encb + (size_t)(m0 + mA[r]) * 512 + aoff + csA[r] * 8);
            async_cp16(Bb + (size_t)(r * 256 + (tid & 192)) * 8,
                       wvT + (size_t)mA[r] * 512 + boff + csA[r] * 8);
        }
    };

    floatx4 acc2[2] = {};

    stage(0, 0);

    for (int nn = 0; nn < 8; ++nn) {
        const int n0 = nn * 128;
        floatx4 acc[4][4] = {};

        #pragma unroll
        for (int kt = 0; kt < 8; ++kt) {
            const int it = nn * 8 + kt;
            if (kt < 7 || nn < 7)
                stage((it + 1) & 1, it + 1);
            // counted wait: tile it's 8 ops oldest; newest 8 stay in flight
            if (kt == 7 && nn == 7) {
                asm volatile("s_waitcnt vmcnt(0)" ::: "memory");
            } else {
                asm volatile("s_waitcnt vmcnt(8)" ::: "memory");
            }
            __builtin_amdgcn_sched_barrier(0);
            __builtin_amdgcn_s_barrier();          // A: tile it landed

            u16* Ab = (u16*)(smem + (it & 1) * 32768);
            u16* Bb = Ab + 8192;
            __builtin_amdgcn_s_setprio(1);
            #pragma unroll
            for (int s2 = 0; s2 < 2; ++s2) {
                bf16x8 af[4], bfr[4];
                #pragma unroll
                for (int mt = 0; mt < 4; ++mt) {
                    const int ma = wr * 64 + mt * 16 + fr;
                    const int ca = (s2 * 4 + quad) ^ (ma & 7);
                    af[mt] = *(const bf16x8*)&Ab[ma * 64 + ca * 8];
                }
                #pragma unroll
                for (int nt = 0; nt < 4; ++nt) {
                    const int nb = wc * 64 + nt * 16 + fr;
                    const int cb = (s2 * 4 + quad) ^ (nb & 7);
                    bfr[nt] = *(const bf16x8*)&Bb[nb * 64 + cb * 8];
                }
                #pragma unroll
                for (int mt = 0; mt < 4; ++mt)
                    #pragma unroll
                    for (int nt = 0; nt < 4; ++nt)
                        acc[mt][nt] = __builtin_amdgcn_mfma_f32_16x16x32_bf16(
                            af[mt], bfr[nt], acc[mt][nt], 0, 0, 0);
            }
            __builtin_amdgcn_s_setprio(0);
            __builtin_amdgcn_sched_barrier(0);
            __builtin_amdgcn_s_barrier();          // B: buf (it&1) free
        }

        // ---- epilogue operands: qv from LDS (cheap), wfr from L1-resident wfb2
        float qv[4];
        bf16x8 wfr[4];
        #pragma unroll
        for (int nt = 0; nt < 4; ++nt)
            qv[nt] = s_qv[n0 + wc * 64 + nt * 16 + fr];
        #pragma unroll
        for (int ks = 0; ks < 4; ++ks)
            wfr[ks] = *(const bf16x8*)&wfb2[((nn * 4 + ks) * 4 + quad) * 64
                                            + (fr & 7) * 8];

        // ---- epilogue A: t = tanh(value + query) -> tT (bf16, XOR-swizzled)
        #pragma unroll
        for (int mt = 0; mt < 4; ++mt) {
            #pragma unroll
            for (int nt = 0; nt < 4; ++nt) {
                const int col = wc * 64 + nt * 16 + fr;
                #pragma unroll
                for (int reg = 0; reg < 4; ++reg) {
                    const int row = wr * 64 + mt * 16 + quad * 4 + reg;
                    ((__bf16*)tT)[row * 128 + (col ^ ((row & 7) << 3))] =
                        (__bf16)tanh_fast(acc[mt][nt][reg] + qv[nt]);
                }
            }
        }
        asm volatile("s_waitcnt lgkmcnt(0)" ::: "memory");
        __builtin_amdgcn_sched_barrier(0);
        __builtin_amdgcn_s_barrier();              // C: tT visible

        // ---- epilogue B: stage-2 MFMA  P += t(128x128) @ Wf_slice(128x8)
        #pragma unroll
        for (int t = 0; t < 2; ++t) {
            const int row = w * 32 + t * 16 + fr;
            #pragma unroll
            for (int ks = 0; ks < 4; ++ks) {
                const bf16x8 ta = *(const bf16x8*)
                    &tT[row * 128 + ((ks * 32 + quad * 8) ^ ((row & 7) << 3))];
                acc2[t] = __builtin_amdgcn_mfma_f32_16x16x32_bf16(ta, wfr[ks], acc2[t], 0, 0, 0);
            }
        }
        __builtin_amdgcn_sched_barrier(0);
        __builtin_amdgcn_s_barrier();              // D: tT reads done before
                                                   //    next nn stages buf1
    }

    // ---- score: softplus(P + bf) * mask * exp(-beta*(kappa-u)^2) -> s_score
    if (fr < NHEADS) {
        const float bfh = bf_g[fr];
        const float bet = beta_ws[b * NHEADS + fr];
        const float kap = kappa_out[b * NHEADS + fr];
        #pragma unroll
        for (int t = 0; t < 2; ++t) {
            #pragma unroll
            for (int reg = 0; reg < 4; ++reg) {
                const int row  = w * 32 + t * 16 + quad * 4 + reg;  // 0..127
                const int grow = m0 + row;
                const int s = grow & 2047;
                const float alpha = softplus_f(acc2[t][reg] + bfh) * mask[grow];
                const float du = kap - (float)s;
                s_score[row * NHEADS + fr] = alpha * __expf(-bet * du * du);
            }
        }
    }
    asm volatile("s_waitcnt lgkmcnt(0)" ::: "memory");
    __builtin_amdgcn_s_barrier();

    // ---- coalesced score store: one contiguous 4KB block
    {
        const float4* src4 = (const float4*)s_score;
        float4* dst4 = (float4*)(score_out + (size_t)m0 * NHEADS);
        dst4[tid] = src4[tid];     // 256 threads x 16B = 4KB = 128x8 floats
    }

    // ---- fused context partial over this block's 128 rows:
    //      part[sc][b][h][e] = sum_s score[s,h] * enc[s,e]
    //      16-deep load batching (enc_bf re-read misses L2: 8MB/XCD > 4MB).
    {
        float acc0[8] = {}, acc1[8] = {};
        const u16* ep = encb + (size_t)m0 * 512 + lane * 8;
        for (int s0 = 0; s0 < 128; s0 += 16) {
            u16x8 ev[16];
            #pragma unroll
            for (int u = 0; u < 16; ++u)
                ev[u] = *(const u16x8*)(ep + (size_t)(s0 + u) * 512);
            #pragma unroll
            for (int u = 0; u < 16; ++u) {
                const float2 sc2 = *(const float2*)&s_score[(s0 + u) * NHEADS + 2 * w];
                #pragma unroll
                for (int j = 0; j < 8; ++j) {
                    const float e = bf2f(ev[u][j]);
                    acc0[j] = fmaf(sc2.x, e, acc0[j]);
                    acc1[j] = fmaf(sc2.y, e, acc1[j]);
                }
            }
        }
        const int e8 = lane * 8;
        float* outp = ctx_part + ((size_t)sc * BSZ + b) * (NHEADS * ENCD);
        *(float4*)&outp[(2 * w + 0) * ENCD + e8]     = make_float4(acc0[0], acc0[1], acc0[2], acc0[3]);
        *(float4*)&outp[(2 * w + 0) * ENCD + e8 + 4] = make_float4(acc0[4], acc0[5], acc0[6], acc0[7]);
        *(float4*)&outp[(2 * w + 1) * ENCD + e8]     = make_float4(acc1[0], acc1[1], acc1[2], acc1[3]);
        *(float4*)&outp[(2 * w + 1) * ENCD + e8 + 4] = make_float4(acc1[4], acc1[5], acc1[6], acc1[7]);
    }
}

// ---------------------------------------------------------------------------
// ctx_ws[i] = sum_sc part[sc][i]   (i < 131072)
// ctx_ws aliases qpart (lifetimes disjoint: qpart dead after gemm).
// ---------------------------------------------------------------------------
__global__ __launch_bounds__(256) void ctx_reduce_kernel(
    const float* __restrict__ part, float* __restrict__ ctx_ws)
{
    const int i = blockIdx.x * 256 + threadIdx.x;
    float a = 0.f;
    #pragma unroll
    for (int sc = 0; sc < 16; ++sc)
        a += part[(size_t)sc * 131072 + i];
    ctx_ws[i] = a;
}

// ---------------------------------------------------------------------------
// out_ctx[b,j] += ctx[b, k0..k0+128] @ Wfc[k0..k0+128, j]  (+bfc at ks==0)
// grid (16, 32): 512 blocks = 2/CU.
// ---------------------------------------------------------------------------
__global__ __launch_bounds__(256) void final_kernel(
    const float* __restrict__ ctx_ws, const float* __restrict__ Wfc,
    const float* __restrict__ bfc, float* __restrict__ out_ctx)
{
    __shared__ float s_ctx[32][128];
    const int jc = blockIdx.x, ks = blockIdx.y, tid = threadIdx.x;
    const int jl = tid & 31, bg = tid >> 5;
    const int j = jc * 32 + jl;
    const int k0 = ks * 128;

    for (int i = tid; i < 32 * 128; i += 256) {
        const int bb2 = i >> 7, kk = i & 127;
        s_ctx[bb2][kk] = ctx_ws[(size_t)bb2 * (NHEADS * ENCD) + k0 + kk];
    }
    __syncthreads();

    float a0 = 0.f, a1 = 0.f, a2 = 0.f, a3 = 0.f;
    for (int kk = 0; kk < 128; ++kk) {
        const float wv = Wfc[(size_t)(k0 + kk) * ENCD + j];
        a0 = fmaf(s_ctx[bg * 4 + 0][kk], wv, a0);
        a1 = fmaf(s_ctx[bg * 4 + 1][kk], wv, a1);
        a2 = fmaf(s_ctx[bg * 4 + 2][kk], wv, a2);
        a3 = fmaf(s_ctx[bg * 4 + 3][kk], wv, a3);
    }
    const float bias = (ks == 0) ? bfc[j] : 0.0f;
    atomicAdd(&out_ctx[(bg * 4 + 0) * ENCD + j], a0 + bias);
    atomicAdd(&out_ctx[(bg * 4 + 1) * ENCD + j], a1 + bias);
    atomicAdd(&out_ctx[(bg * 4 + 2) * ENCD + j], a2 + bias);
    atomicAdd(&out_ctx[(bg * 4 + 3) * ENCD + j], a3 + bias);
}

// ---------------------------------------------------------------------------
extern "C" void kernel_launch(void* const* d_in, const int* in_sizes, int n_in,
                              void* d_out, int out_size, void* d_ws, size_t ws_size,
                              hipStream_t stream)
{
    const float* enc   = (const float*)d_in[0];
    const float* dec   = (const float*)d_in[1];
    const float* kapin = (const float*)d_in[2];
    const float* mask  = (const float*)d_in[3];
    const float* Wv    = (const float*)d_in[4];
    const float* bv    = (const float*)d_in[5];
    const float* Wq    = (const float*)d_in[6];
    const float* bq    = (const float*)d_in[7];
    const float* Wf    = (const float*)d_in[8];
    const float* bf    = (const float*)d_in[9];
    const float* Wb    = (const float*)d_in[10];
    const float* bb    = (const float*)d_in[11];
    const float* Wk    = (const float*)d_in[12];
    const float* bk    = (const float*)d_in[13];
    const float* Wfc   = (const float*)d_in[14];
    const float* bfc   = (const float*)d_in[15];

    // outputs: context(32*512) | kappa(32*8) | score(32*2048*8)
    float* out       = (float*)d_out;
    float* out_ctx   = out;
    float* out_kappa = out + 16384;
    float* out_score = out + 16640;

    // workspace layout (bytes) -- total unchanged at 77218832
    char* w = (char*)d_ws;
    u16*   enc_bf   = (u16*)w;                     // 67108864 B
    float* ctx_part = (float*)(w + 67108864);      //  8388608 B
    u16*   wvT      = (u16*)(w + 75497472);        //  1048576 B
    // (w + 76546048): 131072 B free
    float* beta_ws  = (float*)(w + 76677120);      //     1024 B
    float* qpart    = (float*)(w + 76678144);      //   524288 B (pre->gemm)
    float* ctx_ws   = (float*)(w + 76678144);      //   524288 B (reduce->final)
    u16*   wfb      = (u16*)(w + 77202432);        //    16400 B (16384 used)

    hipMemsetAsync(out_ctx, 0, 16384 * sizeof(float), stream);

    pre_kernel<<<dim3(289), dim3(256), 0, stream>>>(
        Wv, Wf, wvT, wfb,
        dec, kapin, Wq, Wb, bb, Wk, bk, qpart, beta_ws, out_kappa);

    gemm_score_ctx_kernel<<<dim3((BSZ * SEQL) / BM), dim3(256), 0, stream>>>(
        enc, enc_bf, wvT, wfb, bf, mask, qpart, bq, bv, beta_ws, out_kappa,
        out_score, ctx_part);

    ctx_reduce_kernel<<<dim3(512), dim3(256), 0, stream>>>(ctx_part, ctx_ws);

    final_kernel<<<dim3(16, 32), dim3(256), 0, stream>>>(
        ctx_ws, Wfc, bfc, out_ctx);
}